// Round 2
// baseline (463.811 us; speedup 1.0000x reference)
//
#include <hip/hip_runtime.h>
#include <hip/hip_bf16.h>
#include <math.h>

// Problem constants (fixed by setup_inputs)
#define N_NODES   50000
#define N_EDGES   800000
#define N_REL     1000
#define DIM       128
#define DEPTH_L   2
#define OUT_STRIDE (DIM * (DEPTH_L + 1))   // 384

// ---------------------------------------------------------------------------
// Kernel 1: per-relation precompute.
//   rel_hat[r]   = rel_emb[r] / max(||rel_emb[r]||, 1e-12)      [R, D]
//   att_rel[l][r]= rel_hat[r] . attn_k[l]                       [DEPTH, R]
// ---------------------------------------------------------------------------
__global__ __launch_bounds__(64) void prep_rel_kernel(
    const float* __restrict__ rel_emb,
    const float* __restrict__ attn_k,
    float* __restrict__ rel_hat,
    float* __restrict__ att_rel)
{
    int r = blockIdx.x;
    int lane = threadIdx.x;
    float v0 = rel_emb[r * DIM + lane];
    float v1 = rel_emb[r * DIM + lane + 64];
    float ss = v0 * v0 + v1 * v1;
    #pragma unroll
    for (int o = 32; o >= 1; o >>= 1) ss += __shfl_xor(ss, o);
    float inv = 1.0f / fmaxf(sqrtf(ss), 1e-12f);
    float t0 = v0 * inv, t1 = v1 * inv;
    rel_hat[r * DIM + lane]      = t0;
    rel_hat[r * DIM + lane + 64] = t1;
    #pragma unroll
    for (int l = 0; l < DEPTH_L; ++l) {
        float d = t0 * attn_k[l * DIM + lane] + t1 * attn_k[l * DIM + lane + 64];
        #pragma unroll
        for (int o = 32; o >= 1; o >>= 1) d += __shfl_xor(d, o);
        if (lane == 0) att_rel[l * N_REL + r] = d;
    }
}

// ---------------------------------------------------------------------------
// Kernel 2: CSR row pointers from the sorted src array (binary search).
// ---------------------------------------------------------------------------
__global__ __launch_bounds__(256) void rowptr_kernel(
    const int* __restrict__ src, int* __restrict__ rp)
{
    int n = blockIdx.x * blockDim.x + threadIdx.x;
    if (n > N_NODES) return;
    int lo = 0, hi = N_EDGES;
    while (lo < hi) {
        int mid = (lo + hi) >> 1;
        if (src[mid] < n) lo = mid + 1; else hi = mid;
    }
    rp[n] = lo;
}

// ---------------------------------------------------------------------------
// Kernel 3: pack per-edge (dst, rel) with rel=-1 encoding r_val==0.
// ---------------------------------------------------------------------------
__global__ __launch_bounds__(256) void einfo_kernel(
    const int* __restrict__ dst, const int* __restrict__ relid,
    const float* __restrict__ rval, int2* __restrict__ einfo)
{
    int e = blockIdx.x * 256 + threadIdx.x;
    if (e >= N_EDGES) return;
    int r = (rval[e] == 0.f) ? -1 : relid[e];
    einfo[e] = make_int2(dst[e], r);
}

// ---------------------------------------------------------------------------
// Kernel 4: out[:, 0:128] = tanh(features)
// ---------------------------------------------------------------------------
__global__ __launch_bounds__(256) void tanh0_kernel(
    const float* __restrict__ feat, float* __restrict__ out)
{
    int i = blockIdx.x * blockDim.x + threadIdx.x;      // over N*D/4 float4s
    if (i >= N_NODES * DIM / 4) return;
    float4 v = reinterpret_cast<const float4*>(feat)[i];
    int n = (i * 4) / DIM;
    int d = (i * 4) % DIM;
    float4 o;
    o.x = tanhf(v.x); o.y = tanhf(v.y); o.z = tanhf(v.z); o.w = tanhf(v.w);
    *reinterpret_cast<float4*>(&out[(size_t)n * OUT_STRIDE + d]) = o;
}

// ---------------------------------------------------------------------------
// Kernel 5: per-node softmax weights for BOTH layers (feature-independent).
// One wave per node. Writes wc_l[e].x = softmax weight.
// ---------------------------------------------------------------------------
__global__ __launch_bounds__(256) void weights_kernel(
    const int2* __restrict__ einfo, const int* __restrict__ rp,
    const float* __restrict__ att_rel,
    float2* __restrict__ wc0, float2* __restrict__ wc1)
{
    int wid  = threadIdx.x >> 6;
    int lane = threadIdx.x & 63;
    int node = blockIdx.x * 4 + wid;
    if (node >= N_NODES) return;
    int start = rp[node], end = rp[node + 1];
    if (start >= end) return;

    #pragma unroll
    for (int l = 0; l < DEPTH_L; ++l) {
        const float* ar = att_rel + l * N_REL;
        float2* wc = (l == 0) ? wc0 : wc1;
        float m = -INFINITY, s = 0.f;
        for (int e = start + lane; e < end; e += 64) {
            int r = einfo[e].y;
            float logit = (r < 0) ? 0.f : ar[r];
            if (logit > m) { s = s * __expf(m - logit) + 1.f; m = logit; }
            else           { s += __expf(logit - m); }
        }
        #pragma unroll
        for (int o = 32; o >= 1; o >>= 1) {
            float m2 = __shfl_xor(m, o);
            float s2 = __shfl_xor(s, o);
            float mn = fmaxf(m, m2);
            float sn = (mn == -INFINITY) ? 0.f
                     : s * __expf(m - mn) + s2 * __expf(m2 - mn);
            m = mn; s = sn;
        }
        float inv_s = 1.0f / s;
        for (int e = start + lane; e < end; e += 64) {
            int r = einfo[e].y;
            float logit = (r < 0) ? 0.f : ar[r];
            wc[e].x = __expf(logit - m) * inv_s;
        }
    }
}

// ---------------------------------------------------------------------------
// Kernel 6 (per layer): edge-parallel reflection coefficient.
//   c_e = -2 * w_e * (h_dst(e) . rel_hat[rel_e]);  writes wc[e] = (w, c).
// 4 lanes per edge, 32 dims each (8x float4).
// ---------------------------------------------------------------------------
__global__ __launch_bounds__(256) void dot_kernel(
    const float* __restrict__ feat_in,
    const int2* __restrict__ einfo,
    const float* __restrict__ rel_hat,
    float2* __restrict__ wc)
{
    int t = blockIdx.x * 256 + threadIdx.x;
    int e = t >> 2;
    int q = t & 3;
    if (e >= N_EDGES) return;
    int2 ei = einfo[e];
    float w = wc[e].x;
    float c = 0.f;
    if (ei.y >= 0) {
        const float4* h4 = reinterpret_cast<const float4*>(
            feat_in + (size_t)ei.x * OUT_STRIDE) + q * 8;
        const float4* t4 = reinterpret_cast<const float4*>(
            rel_hat + (size_t)ei.y * DIM) + q * 8;
        float4 a = make_float4(0.f, 0.f, 0.f, 0.f);
        #pragma unroll
        for (int k = 0; k < 8; ++k) {
            float4 h = h4[k], tt = t4[k];
            a.x += h.x * tt.x; a.y += h.y * tt.y;
            a.z += h.z * tt.z; a.w += h.w * tt.w;
        }
        float d = (a.x + a.y) + (a.z + a.w);
        d += __shfl_xor(d, 1);
        d += __shfl_xor(d, 2);
        c = -2.f * w * d;
    }
    if (q == 0) wc[e] = make_float2(w, c);
}

// ---------------------------------------------------------------------------
// Kernel 7 (per layer): node-parallel accumulate — NO cross-lane ops.
//   acc[d] = sum_e ( w_e * h_e[d] + c_e * t_e[d] );  out = tanh(acc)
// One wave per node; lane owns dims (2*lane, 2*lane+1).
// ---------------------------------------------------------------------------
__global__ __launch_bounds__(256) void accum_kernel(
    const float* __restrict__ feat_in,
    float* __restrict__ feat_out,
    const int2* __restrict__ einfo,
    const float2* __restrict__ wc,
    const int* __restrict__ rp,
    const float* __restrict__ rel_hat)
{
    int wid  = threadIdx.x >> 6;
    int lane = threadIdx.x & 63;
    int node = blockIdx.x * 4 + wid;
    if (node >= N_NODES) return;
    int start = rp[node], end = rp[node + 1];
    int d2 = 2 * lane;
    float ax = 0.f, ay = 0.f;
    #pragma unroll 4
    for (int e = start; e < end; ++e) {
        int2 ei = einfo[e];
        float2 wce = wc[e];
        float2 h = *reinterpret_cast<const float2*>(
            feat_in + (size_t)ei.x * OUT_STRIDE + d2);
        float2 tt = make_float2(0.f, 0.f);
        if (ei.y >= 0)
            tt = *reinterpret_cast<const float2*>(rel_hat + (size_t)ei.y * DIM + d2);
        ax += wce.x * h.x + wce.y * tt.x;
        ay += wce.x * h.y + wce.y * tt.y;
    }
    *reinterpret_cast<float2*>(feat_out + (size_t)node * OUT_STRIDE + d2)
        = make_float2(tanhf(ax), tanhf(ay));
}

// ---------------------------------------------------------------------------
extern "C" void kernel_launch(void* const* d_in, const int* in_sizes, int n_in,
                              void* d_out, int out_size, void* d_ws, size_t ws_size,
                              hipStream_t stream)
{
    const float* features = (const float*)d_in[0];
    const float* rel_emb  = (const float*)d_in[1];
    const int*   adj      = (const int*)d_in[2];   // [2, E]: src | dst
    const int*   r_index  = (const int*)d_in[3];   // [2, E]: arange | rel
    const float* r_val    = (const float*)d_in[4];
    const float* attn_k   = (const float*)d_in[8]; // [DEPTH, D]
    float* out = (float*)d_out;

    const int* src   = adj;
    const int* dst   = adj + N_EDGES;
    const int* relid = r_index + N_EDGES;

    // Workspace carve-up (~20 MB)
    char* base = (char*)d_ws;
    float* rel_hat = (float*)base;                          // 1000*128*4 = 512000 B
    float* att_rel = rel_hat + (size_t)N_REL * DIM;         // 2*1000*4   =   8000 B
    int*   rp      = (int*)(att_rel + DEPTH_L * N_REL);     // 50001*4    = 200004 B
    size_t off = (512000 + 8000 + 200004 + 15) & ~(size_t)15;
    int2*   einfo = (int2*)(base + off);                    // 800000*8 = 6.4 MB
    float2* wc0   = (float2*)(base + off + (size_t)N_EDGES * 8);
    float2* wc1   = wc0 + N_EDGES;

    prep_rel_kernel<<<N_REL, 64, 0, stream>>>(rel_emb, attn_k, rel_hat, att_rel);
    rowptr_kernel<<<(N_NODES + 1 + 255) / 256, 256, 0, stream>>>(src, rp);
    einfo_kernel<<<(N_EDGES + 255) / 256, 256, 0, stream>>>(dst, relid, r_val, einfo);
    tanh0_kernel<<<(N_NODES * DIM / 4 + 255) / 256, 256, 0, stream>>>(features, out);
    weights_kernel<<<(N_NODES + 3) / 4, 256, 0, stream>>>(einfo, rp, att_rel, wc0, wc1);

    for (int l = 0; l < DEPTH_L; ++l) {
        const float* fin = out + l * DIM;
        float*       fout = out + (l + 1) * DIM;
        float2*      wc = (l == 0) ? wc0 : wc1;
        dot_kernel<<<(N_EDGES * 4 + 255) / 256, 256, 0, stream>>>(fin, einfo, rel_hat, wc);
        accum_kernel<<<(N_NODES + 3) / 4, 256, 0, stream>>>(fin, fout, einfo, wc, rp, rel_hat);
    }
}

// Round 3
// 194.487 us; speedup vs baseline: 2.3848x; 2.3848x over previous
//
#include <hip/hip_runtime.h>
#include <hip/hip_bf16.h>
#include <math.h>

// Problem constants (fixed by setup_inputs)
#define N_NODES   50000
#define N_EDGES   800000
#define N_REL     1000
#define DIM       128
#define DEPTH_L   2
#define OUT_STRIDE (DIM * (DEPTH_L + 1))   // 384

// ---------------------------------------------------------------------------
// Kernel 1: per-relation precompute.
//   rel_hat[r]   = rel_emb[r] / max(||rel_emb[r]||, 1e-12)      [R, D]
//   att_rel[l][r]= rel_hat[r] . attn_k[l]                       [DEPTH, R]
// ---------------------------------------------------------------------------
__global__ __launch_bounds__(64) void prep_rel_kernel(
    const float* __restrict__ rel_emb,
    const float* __restrict__ attn_k,
    float* __restrict__ rel_hat,
    float* __restrict__ att_rel)
{
    int r = blockIdx.x;
    int lane = threadIdx.x;
    float v0 = rel_emb[r * DIM + lane];
    float v1 = rel_emb[r * DIM + lane + 64];
    float ss = v0 * v0 + v1 * v1;
    #pragma unroll
    for (int o = 32; o >= 1; o >>= 1) ss += __shfl_xor(ss, o);
    float inv = 1.0f / fmaxf(sqrtf(ss), 1e-12f);
    float t0 = v0 * inv, t1 = v1 * inv;
    rel_hat[r * DIM + lane]      = t0;
    rel_hat[r * DIM + lane + 64] = t1;
    #pragma unroll
    for (int l = 0; l < DEPTH_L; ++l) {
        float d = t0 * attn_k[l * DIM + lane] + t1 * attn_k[l * DIM + lane + 64];
        #pragma unroll
        for (int o = 32; o >= 1; o >>= 1) d += __shfl_xor(d, o);
        if (lane == 0) att_rel[l * N_REL + r] = d;
    }
}

// ---------------------------------------------------------------------------
// Kernel 2: CSR row pointers from the sorted src array (binary search).
// ---------------------------------------------------------------------------
__global__ __launch_bounds__(256) void rowptr_kernel(
    const int* __restrict__ src, int* __restrict__ rp)
{
    int n = blockIdx.x * blockDim.x + threadIdx.x;
    if (n > N_NODES) return;
    int lo = 0, hi = N_EDGES;
    while (lo < hi) {
        int mid = (lo + hi) >> 1;
        if (src[mid] < n) lo = mid + 1; else hi = mid;
    }
    rp[n] = lo;
}

// ---------------------------------------------------------------------------
// Kernel 3: pack per-edge (dst, rel) with rel=-1 encoding r_val==0.
// ---------------------------------------------------------------------------
__global__ __launch_bounds__(256) void einfo_kernel(
    const int* __restrict__ dst, const int* __restrict__ relid,
    const float* __restrict__ rval, int2* __restrict__ einfo)
{
    int e = blockIdx.x * 256 + threadIdx.x;
    if (e >= N_EDGES) return;
    int r = (rval[e] == 0.f) ? -1 : relid[e];
    einfo[e] = make_int2(dst[e], r);
}

// ---------------------------------------------------------------------------
// Kernel 4: out[:, 0:128] = tanh(features)
// ---------------------------------------------------------------------------
__global__ __launch_bounds__(256) void tanh0_kernel(
    const float* __restrict__ feat, float* __restrict__ out)
{
    int i = blockIdx.x * blockDim.x + threadIdx.x;      // over N*D/4 float4s
    if (i >= N_NODES * DIM / 4) return;
    float4 v = reinterpret_cast<const float4*>(feat)[i];
    int n = (i * 4) / DIM;
    int d = (i * 4) % DIM;
    float4 o;
    o.x = tanhf(v.x); o.y = tanhf(v.y); o.z = tanhf(v.z); o.w = tanhf(v.w);
    *reinterpret_cast<float4*>(&out[(size_t)n * OUT_STRIDE + d]) = o;
}

// ---------------------------------------------------------------------------
// Kernel 5: per-node softmax weights for BOTH layers (feature-independent).
// One wave per node. Writes w_l[e] = softmax weight of edge e in layer l.
// ---------------------------------------------------------------------------
__global__ __launch_bounds__(256) void weights_kernel(
    const int2* __restrict__ einfo, const int* __restrict__ rp,
    const float* __restrict__ att_rel,
    float* __restrict__ w0, float* __restrict__ w1)
{
    int wid  = threadIdx.x >> 6;
    int lane = threadIdx.x & 63;
    int node = blockIdx.x * 4 + wid;
    if (node >= N_NODES) return;
    int start = rp[node], end = rp[node + 1];
    if (start >= end) return;

    #pragma unroll
    for (int l = 0; l < DEPTH_L; ++l) {
        const float* ar = att_rel + l * N_REL;
        float* w = (l == 0) ? w0 : w1;
        float m = -INFINITY, s = 0.f;
        for (int e = start + lane; e < end; e += 64) {
            int r = einfo[e].y;
            float logit = (r < 0) ? 0.f : ar[r];
            if (logit > m) { s = s * __expf(m - logit) + 1.f; m = logit; }
            else           { s += __expf(logit - m); }
        }
        #pragma unroll
        for (int o = 32; o >= 1; o >>= 1) {
            float m2 = __shfl_xor(m, o);
            float s2 = __shfl_xor(s, o);
            float mn = fmaxf(m, m2);
            float sn = (mn == -INFINITY) ? 0.f
                     : s * __expf(m - mn) + s2 * __expf(m2 - mn);
            m = mn; s = sn;
        }
        float inv_s = 1.0f / s;
        for (int e = start + lane; e < end; e += 64) {
            int r = einfo[e].y;
            float logit = (r < 0) ? 0.f : ar[r];
            w[e] = __expf(logit - m) * inv_s;
        }
    }
}

// ---------------------------------------------------------------------------
// Kernel 6 (per layer): FUSED gather + reflect + accumulate.
// One wave per node; chunks of 8 edges; 8 lanes per edge; lane owns 16 dims.
//   acc[d] += w_e * h_e[d] - 2 w_e (h_e . t_e) t_e[d]
// Only ONE feature gather per layer; dependence chain per chunk is
// {8 indep float4 loads -> partial dot -> 3 shuffles -> FMAs}.
// ---------------------------------------------------------------------------
__global__ __launch_bounds__(256) void layer_fused_kernel(
    const float* __restrict__ feat_in,
    float* __restrict__ feat_out,
    const int2* __restrict__ einfo,
    const float* __restrict__ wgt,
    const int* __restrict__ rp,
    const float* __restrict__ rel_hat)
{
    int wid  = threadIdx.x >> 6;
    int lane = threadIdx.x & 63;
    int node = blockIdx.x * 4 + wid;
    if (node >= N_NODES) return;
    int start = rp[node], end = rp[node + 1];
    int g = lane >> 3;      // edge slot within chunk (0..7)
    int q = lane & 7;       // dim group: dims [16q, 16q+16)

    float4 a0 = {0,0,0,0}, a1 = {0,0,0,0}, a2 = {0,0,0,0}, a3 = {0,0,0,0};

    for (int e0 = start; e0 < end; e0 += 8) {
        int e = e0 + g;
        bool valid = (e < end);
        int ec = valid ? e : (end - 1);
        int2 ei = einfo[ec];
        float w = valid ? wgt[ec] : 0.f;

        const float4* h4 = reinterpret_cast<const float4*>(
            feat_in + (size_t)ei.x * OUT_STRIDE) + 4 * q;
        float4 h0 = h4[0], h1 = h4[1], h2 = h4[2], h3 = h4[3];

        float4 t0 = {0,0,0,0}, t1 = {0,0,0,0}, t2 = {0,0,0,0}, t3 = {0,0,0,0};
        if (ei.y >= 0) {
            const float4* t4 = reinterpret_cast<const float4*>(
                rel_hat + (size_t)ei.y * DIM) + 4 * q;
            t0 = t4[0]; t1 = t4[1]; t2 = t4[2]; t3 = t4[3];
        }

        float d = h0.x*t0.x + h0.y*t0.y + h0.z*t0.z + h0.w*t0.w
                + h1.x*t1.x + h1.y*t1.y + h1.z*t1.z + h1.w*t1.w
                + h2.x*t2.x + h2.y*t2.y + h2.z*t2.z + h2.w*t2.w
                + h3.x*t3.x + h3.y*t3.y + h3.z*t3.z + h3.w*t3.w;
        d += __shfl_xor(d, 1);
        d += __shfl_xor(d, 2);
        d += __shfl_xor(d, 4);
        float cf = -2.f * w * d;

        a0.x += w*h0.x + cf*t0.x; a0.y += w*h0.y + cf*t0.y;
        a0.z += w*h0.z + cf*t0.z; a0.w += w*h0.w + cf*t0.w;
        a1.x += w*h1.x + cf*t1.x; a1.y += w*h1.y + cf*t1.y;
        a1.z += w*h1.z + cf*t1.z; a1.w += w*h1.w + cf*t1.w;
        a2.x += w*h2.x + cf*t2.x; a2.y += w*h2.y + cf*t2.y;
        a2.z += w*h2.z + cf*t2.z; a2.w += w*h2.w + cf*t2.w;
        a3.x += w*h3.x + cf*t3.x; a3.y += w*h3.y + cf*t3.y;
        a3.z += w*h3.z + cf*t3.z; a3.w += w*h3.w + cf*t3.w;
    }

    // Fold accumulators across the 8 edge-groups (lanes with same q).
    #pragma unroll
    for (int o = 8; o <= 32; o <<= 1) {
        a0.x += __shfl_xor(a0.x, o); a0.y += __shfl_xor(a0.y, o);
        a0.z += __shfl_xor(a0.z, o); a0.w += __shfl_xor(a0.w, o);
        a1.x += __shfl_xor(a1.x, o); a1.y += __shfl_xor(a1.y, o);
        a1.z += __shfl_xor(a1.z, o); a1.w += __shfl_xor(a1.w, o);
        a2.x += __shfl_xor(a2.x, o); a2.y += __shfl_xor(a2.y, o);
        a2.z += __shfl_xor(a2.z, o); a2.w += __shfl_xor(a2.w, o);
        a3.x += __shfl_xor(a3.x, o); a3.y += __shfl_xor(a3.y, o);
        a3.z += __shfl_xor(a3.z, o); a3.w += __shfl_xor(a3.w, o);
    }

    if (g == 0) {
        float* orow = feat_out + (size_t)node * OUT_STRIDE + 16 * q;
        float4 r;
        r.x = tanhf(a0.x); r.y = tanhf(a0.y); r.z = tanhf(a0.z); r.w = tanhf(a0.w);
        reinterpret_cast<float4*>(orow)[0] = r;
        r.x = tanhf(a1.x); r.y = tanhf(a1.y); r.z = tanhf(a1.z); r.w = tanhf(a1.w);
        reinterpret_cast<float4*>(orow)[1] = r;
        r.x = tanhf(a2.x); r.y = tanhf(a2.y); r.z = tanhf(a2.z); r.w = tanhf(a2.w);
        reinterpret_cast<float4*>(orow)[2] = r;
        r.x = tanhf(a3.x); r.y = tanhf(a3.y); r.z = tanhf(a3.z); r.w = tanhf(a3.w);
        reinterpret_cast<float4*>(orow)[3] = r;
    }
}

// ---------------------------------------------------------------------------
extern "C" void kernel_launch(void* const* d_in, const int* in_sizes, int n_in,
                              void* d_out, int out_size, void* d_ws, size_t ws_size,
                              hipStream_t stream)
{
    const float* features = (const float*)d_in[0];
    const float* rel_emb  = (const float*)d_in[1];
    const int*   adj      = (const int*)d_in[2];   // [2, E]: src | dst
    const int*   r_index  = (const int*)d_in[3];   // [2, E]: arange | rel
    const float* r_val    = (const float*)d_in[4];
    const float* attn_k   = (const float*)d_in[8]; // [DEPTH, D]
    float* out = (float*)d_out;

    const int* src   = adj;
    const int* dst   = adj + N_EDGES;
    const int* relid = r_index + N_EDGES;

    // Workspace carve-up (~13.5 MB)
    char* base = (char*)d_ws;
    float* rel_hat = (float*)base;                          // 1000*128*4 = 512000 B
    float* att_rel = rel_hat + (size_t)N_REL * DIM;         // 2*1000*4   =   8000 B
    int*   rp      = (int*)(att_rel + DEPTH_L * N_REL);     // 50001*4    = 200004 B
    size_t off = (512000 + 8000 + 200004 + 15) & ~(size_t)15;
    int2*  einfo = (int2*)(base + off);                     // 800000*8 = 6.4 MB
    float* w0    = (float*)(base + off + (size_t)N_EDGES * 8);
    float* w1    = w0 + N_EDGES;

    prep_rel_kernel<<<N_REL, 64, 0, stream>>>(rel_emb, attn_k, rel_hat, att_rel);
    rowptr_kernel<<<(N_NODES + 1 + 255) / 256, 256, 0, stream>>>(src, rp);
    einfo_kernel<<<(N_EDGES + 255) / 256, 256, 0, stream>>>(dst, relid, r_val, einfo);
    tanh0_kernel<<<(N_NODES * DIM / 4 + 255) / 256, 256, 0, stream>>>(features, out);
    weights_kernel<<<(N_NODES + 3) / 4, 256, 0, stream>>>(einfo, rp, att_rel, w0, w1);

    for (int l = 0; l < DEPTH_L; ++l) {
        layer_fused_kernel<<<(N_NODES + 3) / 4, 256, 0, stream>>>(
            out + l * DIM,          // previous layer's feature block
            out + (l + 1) * DIM,    // this layer's feature block
            einfo, (l == 0) ? w0 : w1, rp, rel_hat);
    }
}

// Round 4
// 148.475 us; speedup vs baseline: 3.1238x; 1.3099x over previous
//
#include <hip/hip_runtime.h>
#include <hip/hip_bf16.h>
#include <math.h>

// Problem constants (fixed by setup_inputs)
#define N_NODES   50000
#define N_EDGES   800000
#define N_REL     1000
#define DIM       128
#define DEPTH_L   2
#define OUT_STRIDE (DIM * (DEPTH_L + 1))   // 384

// ---- bf16 helpers (RNE) ---------------------------------------------------
__device__ __forceinline__ unsigned bf16_rne(float x) {
    unsigned u = __float_as_uint(x);
    unsigned r = ((u >> 16) & 1u) + 0x7fffu;
    return (u + r) >> 16;
}
__device__ __forceinline__ unsigned pack_bf16(float a, float b) {
    return bf16_rne(a) | (bf16_rne(b) << 16);
}
__device__ __forceinline__ void unpack_bf16x8(uint4 u, float* f) {
    f[0] = __uint_as_float(u.x << 16); f[1] = __uint_as_float(u.x & 0xffff0000u);
    f[2] = __uint_as_float(u.y << 16); f[3] = __uint_as_float(u.y & 0xffff0000u);
    f[4] = __uint_as_float(u.z << 16); f[5] = __uint_as_float(u.z & 0xffff0000u);
    f[6] = __uint_as_float(u.w << 16); f[7] = __uint_as_float(u.w & 0xffff0000u);
}

// ---------------------------------------------------------------------------
// Kernel 1: per-relation precompute.
//   rhat[r] = bf16( rel_emb[r] / max(||rel_emb[r]||, 1e-12) )   [R, D]
//   att_rel[l][r] = rhat_f32 . attn_k[l]                        [DEPTH, R]
// ---------------------------------------------------------------------------
__global__ __launch_bounds__(64) void prep_rel_kernel(
    const float* __restrict__ rel_emb,
    const float* __restrict__ attn_k,
    unsigned short* __restrict__ rhat,
    float* __restrict__ att_rel)
{
    int r = blockIdx.x;
    int lane = threadIdx.x;
    float v0 = rel_emb[r * DIM + lane];
    float v1 = rel_emb[r * DIM + lane + 64];
    float ss = v0 * v0 + v1 * v1;
    #pragma unroll
    for (int o = 32; o >= 1; o >>= 1) ss += __shfl_xor(ss, o);
    float inv = 1.0f / fmaxf(sqrtf(ss), 1e-12f);
    float t0 = v0 * inv, t1 = v1 * inv;
    rhat[r * DIM + lane]      = (unsigned short)bf16_rne(t0);
    rhat[r * DIM + lane + 64] = (unsigned short)bf16_rne(t1);
    #pragma unroll
    for (int l = 0; l < DEPTH_L; ++l) {
        float d = t0 * attn_k[l * DIM + lane] + t1 * attn_k[l * DIM + lane + 64];
        #pragma unroll
        for (int o = 32; o >= 1; o >>= 1) d += __shfl_xor(d, o);
        if (lane == 0) att_rel[l * N_REL + r] = d;
    }
}

// ---------------------------------------------------------------------------
// Kernel 2: CSR row pointers from the sorted src array (binary search).
// ---------------------------------------------------------------------------
__global__ __launch_bounds__(256) void rowptr_kernel(
    const int* __restrict__ src, int* __restrict__ rp)
{
    int n = blockIdx.x * blockDim.x + threadIdx.x;
    if (n > N_NODES) return;
    int lo = 0, hi = N_EDGES;
    while (lo < hi) {
        int mid = (lo + hi) >> 1;
        if (src[mid] < n) lo = mid + 1; else hi = mid;
    }
    rp[n] = lo;
}

// ---------------------------------------------------------------------------
// Kernel 3: out[:, 0:128] = tanh(features), plus packed bf16 mirror fs0.
// ---------------------------------------------------------------------------
__global__ __launch_bounds__(256) void tanh0_kernel(
    const float* __restrict__ feat, float* __restrict__ out,
    unsigned short* __restrict__ fs0)
{
    int i = blockIdx.x * blockDim.x + threadIdx.x;   // N*32 threads, 4 dims each
    if (i >= N_NODES * 32) return;
    int n = i >> 5;
    int j = i & 31;
    float4 v = reinterpret_cast<const float4*>(feat + (size_t)n * DIM)[j];
    float4 o;
    o.x = tanhf(v.x); o.y = tanhf(v.y); o.z = tanhf(v.z); o.w = tanhf(v.w);
    reinterpret_cast<float4*>(out + (size_t)n * OUT_STRIDE)[j] = o;
    uint2 p;
    p.x = pack_bf16(o.x, o.y);
    p.y = pack_bf16(o.z, o.w);
    reinterpret_cast<uint2*>(fs0 + (size_t)n * DIM)[j] = p;
}

// ---------------------------------------------------------------------------
// Kernel 4: edge metadata + softmax weights for BOTH layers in one pass.
// One wave per node. einfo[e] = (dst, rel or -1); w_l[e] = softmax weight.
// ---------------------------------------------------------------------------
__global__ __launch_bounds__(256) void weights_kernel(
    const int* __restrict__ dst, const int* __restrict__ relid,
    const float* __restrict__ rval, const int* __restrict__ rp,
    const float* __restrict__ att_rel,
    int2* __restrict__ einfo,
    float* __restrict__ w0, float* __restrict__ w1)
{
    int wid  = threadIdx.x >> 6;
    int lane = threadIdx.x & 63;
    int node = blockIdx.x * 4 + wid;
    if (node >= N_NODES) return;
    int start = rp[node], end = rp[node + 1];
    if (start >= end) return;
    const float* ar0 = att_rel;
    const float* ar1 = att_rel + N_REL;

    float m0 = -INFINITY, s0 = 0.f, m1 = -INFINITY, s1 = 0.f;
    for (int e = start + lane; e < end; e += 64) {
        float rv = rval[e];
        int r = (rv == 0.f) ? -1 : relid[e];
        einfo[e] = make_int2(dst[e], r);
        float l0 = (r < 0) ? 0.f : ar0[r];
        float l1 = (r < 0) ? 0.f : ar1[r];
        if (l0 > m0) { s0 = s0 * __expf(m0 - l0) + 1.f; m0 = l0; }
        else         { s0 += __expf(l0 - m0); }
        if (l1 > m1) { s1 = s1 * __expf(m1 - l1) + 1.f; m1 = l1; }
        else         { s1 += __expf(l1 - m1); }
    }
    #pragma unroll
    for (int o = 32; o >= 1; o >>= 1) {
        float ma = __shfl_xor(m0, o), sa = __shfl_xor(s0, o);
        float mn = fmaxf(m0, ma);
        s0 = (mn == -INFINITY) ? 0.f : s0 * __expf(m0 - mn) + sa * __expf(ma - mn);
        m0 = mn;
        float mb = __shfl_xor(m1, o), sb = __shfl_xor(s1, o);
        float mo = fmaxf(m1, mb);
        s1 = (mo == -INFINITY) ? 0.f : s1 * __expf(m1 - mo) + sb * __expf(mb - mo);
        m1 = mo;
    }
    float i0 = 1.0f / s0, i1 = 1.0f / s1;
    for (int e = start + lane; e < end; e += 64) {
        int r = einfo[e].y;
        float l0 = (r < 0) ? 0.f : ar0[r];
        float l1 = (r < 0) ? 0.f : ar1[r];
        w0[e] = __expf(l0 - m0) * i0;
        w1[e] = __expf(l1 - m1) * i1;
    }
}

// ---------------------------------------------------------------------------
// Kernel 5 (per layer): FUSED gather + reflect + accumulate, bf16 inputs.
// One wave per node; chunks of 8 edges; 8 lanes/edge; lane owns 16 dims.
// Writes f32 to the out column block AND a packed bf16 mirror for next layer.
// ---------------------------------------------------------------------------
__global__ __launch_bounds__(256) void layer_fused_kernel(
    const unsigned short* __restrict__ fs_in,   // [N,128] bf16
    float* __restrict__ fout,                   // column block in d_out
    unsigned short* __restrict__ fs_out,        // [N,128] bf16 mirror
    const int2* __restrict__ einfo,
    const float* __restrict__ wgt,
    const int* __restrict__ rp,
    const unsigned short* __restrict__ rhat)    // [R,128] bf16
{
    int wid  = threadIdx.x >> 6;
    int lane = threadIdx.x & 63;
    int node = blockIdx.x * 4 + wid;
    if (node >= N_NODES) return;
    int start = rp[node], end = rp[node + 1];
    int g = lane >> 3;      // edge slot within chunk (0..7)
    int q = lane & 7;       // dim group: dims [16q, 16q+16)

    float a[16];
    #pragma unroll
    for (int i = 0; i < 16; ++i) a[i] = 0.f;

    for (int e0 = start; e0 < end; e0 += 8) {
        int e = e0 + g;
        bool valid = (e < end);
        int ec = valid ? e : (end - 1);
        int2 ei = einfo[ec];
        float w = valid ? wgt[ec] : 0.f;

        const uint4* hp = reinterpret_cast<const uint4*>(
            fs_in + (size_t)ei.x * DIM + 16 * q);
        uint4 hu0 = hp[0], hu1 = hp[1];
        float h[16];
        unpack_bf16x8(hu0, h);
        unpack_bf16x8(hu1, h + 8);

        float t[16];
        if (ei.y >= 0) {
            const uint4* tp = reinterpret_cast<const uint4*>(
                rhat + (size_t)ei.y * DIM + 16 * q);
            uint4 tu0 = tp[0], tu1 = tp[1];
            unpack_bf16x8(tu0, t);
            unpack_bf16x8(tu1, t + 8);
        } else {
            #pragma unroll
            for (int i = 0; i < 16; ++i) t[i] = 0.f;
        }

        float d = 0.f;
        #pragma unroll
        for (int i = 0; i < 16; ++i) d += h[i] * t[i];
        d += __shfl_xor(d, 1);
        d += __shfl_xor(d, 2);
        d += __shfl_xor(d, 4);
        float cf = -2.f * w * d;

        #pragma unroll
        for (int i = 0; i < 16; ++i) a[i] += w * h[i] + cf * t[i];
    }

    // Fold across the 8 edge-groups; afterwards every lane holds the sums.
    #pragma unroll
    for (int o = 8; o <= 32; o <<= 1) {
        #pragma unroll
        for (int i = 0; i < 16; ++i) a[i] += __shfl_xor(a[i], o);
    }

    // Distributed epilogue: lane (g,q) handles dims 16q+2g, 16q+2g+1.
    float x0 = (g == 0) ? a[0] : (g == 1) ? a[2] : (g == 2) ? a[4] : (g == 3) ? a[6]
             : (g == 4) ? a[8] : (g == 5) ? a[10] : (g == 6) ? a[12] : a[14];
    float x1 = (g == 0) ? a[1] : (g == 1) ? a[3] : (g == 2) ? a[5] : (g == 3) ? a[7]
             : (g == 4) ? a[9] : (g == 5) ? a[11] : (g == 6) ? a[13] : a[15];
    float y0 = tanhf(x0), y1 = tanhf(x1);
    int dimo = 16 * q + 2 * g;
    *reinterpret_cast<float2*>(fout + (size_t)node * OUT_STRIDE + dimo)
        = make_float2(y0, y1);
    *reinterpret_cast<unsigned*>(fs_out + (size_t)node * DIM + dimo)
        = pack_bf16(y0, y1);
}

// ---------------------------------------------------------------------------
extern "C" void kernel_launch(void* const* d_in, const int* in_sizes, int n_in,
                              void* d_out, int out_size, void* d_ws, size_t ws_size,
                              hipStream_t stream)
{
    const float* features = (const float*)d_in[0];
    const float* rel_emb  = (const float*)d_in[1];
    const int*   adj      = (const int*)d_in[2];   // [2, E]: src | dst
    const int*   r_index  = (const int*)d_in[3];   // [2, E]: arange | rel
    const float* r_val    = (const float*)d_in[4];
    const float* attn_k   = (const float*)d_in[8]; // [DEPTH, D]
    float* out = (float*)d_out;

    const int* src   = adj;
    const int* dst   = adj + N_EDGES;
    const int* relid = r_index + N_EDGES;

    // Workspace carve-up (~39 MB)
    char* base = (char*)d_ws;
    unsigned short* rhat = (unsigned short*)base;                 // 1000*128*2 = 256000
    float* att_rel = (float*)(base + 256000);                     // 2*1000*4   =   8000
    int*   rp      = (int*)(base + 256000 + 8000);                // 50001*4    = 200004
    size_t off = (256000 + 8000 + 200004 + 15) & ~(size_t)15;
    int2*  einfo = (int2*)(base + off);                           // 6.4 MB
    float* w0    = (float*)(base + off + (size_t)N_EDGES * 8);    // 3.2 MB
    float* w1    = w0 + N_EDGES;                                  // 3.2 MB
    unsigned short* fs0 = (unsigned short*)(w1 + N_EDGES);        // 12.8 MB
    unsigned short* fs1 = fs0 + (size_t)N_NODES * DIM;            // 12.8 MB

    prep_rel_kernel<<<N_REL, 64, 0, stream>>>(rel_emb, attn_k, rhat, att_rel);
    rowptr_kernel<<<(N_NODES + 1 + 255) / 256, 256, 0, stream>>>(src, rp);
    tanh0_kernel<<<(N_NODES * 32 + 255) / 256, 256, 0, stream>>>(features, out, fs0);
    weights_kernel<<<(N_NODES + 3) / 4, 256, 0, stream>>>(
        dst, relid, r_val, rp, att_rel, einfo, w0, w1);

    for (int l = 0; l < DEPTH_L; ++l) {
        layer_fused_kernel<<<(N_NODES + 3) / 4, 256, 0, stream>>>(
            (l == 0) ? fs0 : fs1,
            out + (l + 1) * DIM,
            (l == 0) ? fs1 : fs0,   // layer-2 mirror unused; reuse fs0 slot
            einfo, (l == 0) ? w0 : w1, rp, rhat);
    }
}

// Round 5
// 141.444 us; speedup vs baseline: 3.2791x; 1.0497x over previous
//
#include <hip/hip_runtime.h>
#include <hip/hip_bf16.h>
#include <math.h>

// Problem constants (fixed by setup_inputs)
#define N_NODES   50000
#define N_EDGES   800000
#define N_REL     1000
#define DIM       128
#define DEPTH_L   2
#define OUT_STRIDE (DIM * (DEPTH_L + 1))   // 384

typedef _Float16 h2 __attribute__((ext_vector_type(2)));

#if defined(__has_builtin)
#if __has_builtin(__builtin_amdgcn_fdot2)
#define FDOT2(a, b, c) __builtin_amdgcn_fdot2((a), (b), (c), false)
#endif
#endif
#ifndef FDOT2
#define FDOT2(a, b, c) ((c) + (float)(a).x * (float)(b).x + (float)(a).y * (float)(b).y)
#endif

// fast tanh: (e^{2x}-1)/(e^{2x}+1), clamped so exp never overflows.
__device__ __forceinline__ float fast_tanh(float x) {
    float cx = fminf(fmaxf(x, -15.f), 15.f);
    float e = __expf(2.f * cx);
    return (e - 1.f) * __frcp_rn(e + 1.f);
}

// ---------------------------------------------------------------------------
// Kernel 1: per-relation precompute (R+1 blocks; block N_REL writes the
// zero row used by edges with r_val==0).
//   rhat[r]   = f16( rel_emb[r] / max(||rel_emb[r]||, 1e-12) )  [(R+1), D]
//   att_rel[l][r] = rhat_f32 . attn_k[l]                        [DEPTH, R+1]
// ---------------------------------------------------------------------------
__global__ __launch_bounds__(64) void prep_rel_kernel(
    const float* __restrict__ rel_emb,
    const float* __restrict__ attn_k,
    _Float16* __restrict__ rhat,
    float* __restrict__ att_rel)
{
    int r = blockIdx.x;
    int lane = threadIdx.x;
    if (r == N_REL) {                       // zero row / zero logit slot
        rhat[(size_t)r * DIM + lane]      = (_Float16)0.f;
        rhat[(size_t)r * DIM + lane + 64] = (_Float16)0.f;
        if (lane < DEPTH_L) att_rel[lane * (N_REL + 1) + N_REL] = 0.f;
        return;
    }
    float v0 = rel_emb[r * DIM + lane];
    float v1 = rel_emb[r * DIM + lane + 64];
    float ss = v0 * v0 + v1 * v1;
    #pragma unroll
    for (int o = 32; o >= 1; o >>= 1) ss += __shfl_xor(ss, o);
    float inv = 1.0f / fmaxf(sqrtf(ss), 1e-12f);
    float t0 = v0 * inv, t1 = v1 * inv;
    rhat[(size_t)r * DIM + lane]      = (_Float16)t0;
    rhat[(size_t)r * DIM + lane + 64] = (_Float16)t1;
    #pragma unroll
    for (int l = 0; l < DEPTH_L; ++l) {
        float d = t0 * attn_k[l * DIM + lane] + t1 * attn_k[l * DIM + lane + 64];
        #pragma unroll
        for (int o = 32; o >= 1; o >>= 1) d += __shfl_xor(d, o);
        if (lane == 0) att_rel[l * (N_REL + 1) + r] = d;
    }
}

// ---------------------------------------------------------------------------
// Kernel 2: CSR row pointers from the sorted src array (binary search).
// ---------------------------------------------------------------------------
__global__ __launch_bounds__(256) void rowptr_kernel(
    const int* __restrict__ src, int* __restrict__ rp)
{
    int n = blockIdx.x * blockDim.x + threadIdx.x;
    if (n > N_NODES) return;
    int lo = 0, hi = N_EDGES;
    while (lo < hi) {
        int mid = (lo + hi) >> 1;
        if (src[mid] < n) lo = mid + 1; else hi = mid;
    }
    rp[n] = lo;
}

// ---------------------------------------------------------------------------
// Kernel 3: out[:, 0:128] = tanh(features), plus packed f16 mirror fs0.
// ---------------------------------------------------------------------------
__global__ __launch_bounds__(256) void tanh0_kernel(
    const float* __restrict__ feat, float* __restrict__ out,
    _Float16* __restrict__ fs0)
{
    int i = blockIdx.x * blockDim.x + threadIdx.x;   // N*32 threads, 4 dims each
    if (i >= N_NODES * 32) return;
    int n = i >> 5;
    int j = i & 31;
    float4 v = reinterpret_cast<const float4*>(feat + (size_t)n * DIM)[j];
    float4 o;
    o.x = fast_tanh(v.x); o.y = fast_tanh(v.y);
    o.z = fast_tanh(v.z); o.w = fast_tanh(v.w);
    reinterpret_cast<float4*>(out + (size_t)n * OUT_STRIDE)[j] = o;
    h2 p0; p0.x = (_Float16)o.x; p0.y = (_Float16)o.y;
    h2 p1; p1.x = (_Float16)o.z; p1.y = (_Float16)o.w;
    uint2 u;
    u.x = __builtin_bit_cast(unsigned, p0);
    u.y = __builtin_bit_cast(unsigned, p1);
    reinterpret_cast<uint2*>(fs0 + (size_t)n * DIM)[j] = u;
}

// ---------------------------------------------------------------------------
// Kernel 4: softmax weights for BOTH layers + packed edge record.
//   einfo4[e] = { dst, rel' (N_REL if r_val==0), bits(w0), bits(w1) }
// One wave per node, online softmax, butterfly merge.
// ---------------------------------------------------------------------------
__global__ __launch_bounds__(256) void weights_kernel(
    const int* __restrict__ dst, const int* __restrict__ relid,
    const float* __restrict__ rval, const int* __restrict__ rp,
    const float* __restrict__ att_rel,
    uint4* __restrict__ einfo4)
{
    int wid  = threadIdx.x >> 6;
    int lane = threadIdx.x & 63;
    int node = blockIdx.x * 4 + wid;
    if (node >= N_NODES) return;
    int start = rp[node], end = rp[node + 1];
    if (start >= end) return;
    const float* ar0 = att_rel;
    const float* ar1 = att_rel + (N_REL + 1);

    float m0 = -INFINITY, s0 = 0.f, m1 = -INFINITY, s1 = 0.f;
    for (int e = start + lane; e < end; e += 64) {
        int r = (rval[e] == 0.f) ? N_REL : relid[e];
        float l0 = ar0[r], l1 = ar1[r];
        if (l0 > m0) { s0 = s0 * __expf(m0 - l0) + 1.f; m0 = l0; }
        else         { s0 += __expf(l0 - m0); }
        if (l1 > m1) { s1 = s1 * __expf(m1 - l1) + 1.f; m1 = l1; }
        else         { s1 += __expf(l1 - m1); }
    }
    #pragma unroll
    for (int o = 32; o >= 1; o >>= 1) {
        float ma = __shfl_xor(m0, o), sa = __shfl_xor(s0, o);
        float mn = fmaxf(m0, ma);
        s0 = (mn == -INFINITY) ? 0.f : s0 * __expf(m0 - mn) + sa * __expf(ma - mn);
        m0 = mn;
        float mb = __shfl_xor(m1, o), sb = __shfl_xor(s1, o);
        float mo = fmaxf(m1, mb);
        s1 = (mo == -INFINITY) ? 0.f : s1 * __expf(m1 - mo) + sb * __expf(mb - mo);
        m1 = mo;
    }
    float i0 = 1.0f / s0, i1 = 1.0f / s1;
    for (int e = start + lane; e < end; e += 64) {
        int r = (rval[e] == 0.f) ? N_REL : relid[e];
        float w0 = __expf(ar0[r] - m0) * i0;
        float w1 = __expf(ar1[r] - m1) * i1;
        einfo4[e] = make_uint4((unsigned)dst[e], (unsigned)r,
                               __float_as_uint(w0), __float_as_uint(w1));
    }
}

// ---------------------------------------------------------------------------
// Kernel 5 (per layer L): FUSED gather + reflect + accumulate, f16 inputs.
// One wave per node; chunks of 8 edges; 8 lanes/edge; lane owns 16 dims.
// Dot via v_dot2_f32_f16 on packed pairs; accumulate via v_fma_mix (f32 acc).
// Halving-butterfly fold leaves each lane with its 2 output dims.
// ---------------------------------------------------------------------------
template<int L>
__global__ __launch_bounds__(256) void layer_fused_kernel(
    const _Float16* __restrict__ fs_in,   // [N,128] f16
    float* __restrict__ fout,             // column block in d_out
    _Float16* __restrict__ fs_out,        // [N,128] f16 mirror (L==0 only)
    const uint4* __restrict__ einfo4,
    const int* __restrict__ rp,
    const _Float16* __restrict__ rhat)    // [(R+1),128] f16
{
    int wid  = threadIdx.x >> 6;
    int lane = threadIdx.x & 63;
    int node = blockIdx.x * 4 + wid;
    if (node >= N_NODES) return;
    int start = rp[node], end = rp[node + 1];
    int g = lane >> 3;      // edge slot within chunk (0..7)
    int q = lane & 7;       // dim group: dims [16q, 16q+16)

    float a[16];
    #pragma unroll
    for (int i = 0; i < 16; ++i) a[i] = 0.f;

    const char* fbase = (const char*)fs_in + 32 * q;   // +16 dims * 2B per q
    const char* tbase = (const char*)rhat  + 32 * q;

    for (int e0 = start; e0 < end; e0 += 8) {
        int e = e0 + g;
        bool valid = (e < end);
        int ec = valid ? e : (end - 1);
        uint4 ei = einfo4[ec];
        float w = valid ? __uint_as_float((L == 0) ? ei.z : ei.w) : 0.f;

        const uint4* hp = reinterpret_cast<const uint4*>(fbase + (size_t)ei.x * 256);
        const uint4* tp = reinterpret_cast<const uint4*>(tbase + (size_t)ei.y * 256);
        uint4 hu0 = hp[0], hu1 = hp[1];
        uint4 tu0 = tp[0], tu1 = tp[1];

        h2 hh[8], tt[8];
        hh[0] = __builtin_bit_cast(h2, hu0.x); hh[1] = __builtin_bit_cast(h2, hu0.y);
        hh[2] = __builtin_bit_cast(h2, hu0.z); hh[3] = __builtin_bit_cast(h2, hu0.w);
        hh[4] = __builtin_bit_cast(h2, hu1.x); hh[5] = __builtin_bit_cast(h2, hu1.y);
        hh[6] = __builtin_bit_cast(h2, hu1.z); hh[7] = __builtin_bit_cast(h2, hu1.w);
        tt[0] = __builtin_bit_cast(h2, tu0.x); tt[1] = __builtin_bit_cast(h2, tu0.y);
        tt[2] = __builtin_bit_cast(h2, tu0.z); tt[3] = __builtin_bit_cast(h2, tu0.w);
        tt[4] = __builtin_bit_cast(h2, tu1.x); tt[5] = __builtin_bit_cast(h2, tu1.y);
        tt[6] = __builtin_bit_cast(h2, tu1.z); tt[7] = __builtin_bit_cast(h2, tu1.w);

        float d0 = 0.f, d1 = 0.f;
        #pragma unroll
        for (int p = 0; p < 8; p += 2) {
            d0 = FDOT2(hh[p],     tt[p],     d0);
            d1 = FDOT2(hh[p + 1], tt[p + 1], d1);
        }
        float d = d0 + d1;
        d += __shfl_xor(d, 1);
        d += __shfl_xor(d, 2);
        d += __shfl_xor(d, 4);
        float cf = -2.f * w * d;

        #pragma unroll
        for (int p = 0; p < 8; ++p) {
            a[2*p]   = fmaf(w,  (float)hh[p].x, a[2*p]);
            a[2*p]   = fmaf(cf, (float)tt[p].x, a[2*p]);
            a[2*p+1] = fmaf(w,  (float)hh[p].y, a[2*p+1]);
            a[2*p+1] = fmaf(cf, (float)tt[p].y, a[2*p+1]);
        }
    }

    // Halving butterfly over the 8 edge-groups. After 3 steps, lane (g,q)
    // holds the full sums for dims 16q+2g, 16q+2g+1.
    int g0 = (lane >> 3) & 1, g1 = (lane >> 4) & 1, g2 = (lane >> 5) & 1;
    float b1[8];
    #pragma unroll
    for (int j = 0; j < 8; ++j) {
        int J0 = ((j >> 2) & 1) * 8 + ((j >> 1) & 1) * 4 + (j & 1);
        float keep = g0 ? a[J0 + 2] : a[J0];
        float send = g0 ? a[J0] : a[J0 + 2];
        b1[j] = keep + __shfl_xor(send, 8);
    }
    float b2[4];
    #pragma unroll
    for (int k = 0; k < 4; ++k) {
        int K0 = ((k >> 1) & 1) * 4 + (k & 1);
        float keep = g1 ? b1[K0 + 2] : b1[K0];
        float send = g1 ? b1[K0] : b1[K0 + 2];
        b2[k] = keep + __shfl_xor(send, 16);
    }
    float c0, c1;
    {
        float keep = g2 ? b2[2] : b2[0];
        float send = g2 ? b2[0] : b2[2];
        c0 = keep + __shfl_xor(send, 32);
    }
    {
        float keep = g2 ? b2[3] : b2[1];
        float send = g2 ? b2[1] : b2[3];
        c1 = keep + __shfl_xor(send, 32);
    }

    float y0 = fast_tanh(c0), y1 = fast_tanh(c1);
    int dimo = 16 * q + 2 * g;
    *reinterpret_cast<float2*>(fout + (size_t)node * OUT_STRIDE + dimo)
        = make_float2(y0, y1);
    if (L == 0) {
        h2 pr; pr.x = (_Float16)y0; pr.y = (_Float16)y1;
        *reinterpret_cast<h2*>(fs_out + (size_t)node * DIM + dimo) = pr;
    }
}

// ---------------------------------------------------------------------------
extern "C" void kernel_launch(void* const* d_in, const int* in_sizes, int n_in,
                              void* d_out, int out_size, void* d_ws, size_t ws_size,
                              hipStream_t stream)
{
    const float* features = (const float*)d_in[0];
    const float* rel_emb  = (const float*)d_in[1];
    const int*   adj      = (const int*)d_in[2];   // [2, E]: src | dst
    const int*   r_index  = (const int*)d_in[3];   // [2, E]: arange | rel
    const float* r_val    = (const float*)d_in[4];
    const float* attn_k   = (const float*)d_in[8]; // [DEPTH, D]
    float* out = (float*)d_out;

    const int* src   = adj;
    const int* dst   = adj + N_EDGES;
    const int* relid = r_index + N_EDGES;

    // Workspace carve-up (~39 MB)
    char* base = (char*)d_ws;
    _Float16* rhat   = (_Float16*)base;                 // (R+1)*128*2 = 256256 B
    float*    att_rel = (float*)(base + 256256);        // 2*(R+1)*4   =   8008 B
    int*      rp      = (int*)(base + 264264);          // 50001*4     = 200004 B
    uint4*    einfo4  = (uint4*)(base + 464272);        // 800000*16   = 12.8 MB
    _Float16* fs0     = (_Float16*)(base + 464272 + (size_t)N_EDGES * 16); // 12.8 MB
    _Float16* fs1     = fs0 + (size_t)N_NODES * DIM;                       // 12.8 MB

    prep_rel_kernel<<<N_REL + 1, 64, 0, stream>>>(rel_emb, attn_k, rhat, att_rel);
    rowptr_kernel<<<(N_NODES + 1 + 255) / 256, 256, 0, stream>>>(src, rp);
    tanh0_kernel<<<(N_NODES * 32 + 255) / 256, 256, 0, stream>>>(features, out, fs0);
    weights_kernel<<<(N_NODES + 3) / 4, 256, 0, stream>>>(
        dst, relid, r_val, rp, att_rel, einfo4);

    layer_fused_kernel<0><<<(N_NODES + 3) / 4, 256, 0, stream>>>(
        fs0, out + 1 * DIM, fs1, einfo4, rp, rhat);
    layer_fused_kernel<1><<<(N_NODES + 3) / 4, 256, 0, stream>>>(
        fs1, out + 2 * DIM, fs0, einfo4, rp, rhat);
}